// Round 1
// baseline (95.599 us; speedup 1.0000x reference)
//
#include <hip/hip_runtime.h>
#include <hip/hip_bf16.h>
#include <math.h>

#define N_FEAT 6272
#define DIM    128
#define M_BANK 30000
#define M_PAD  30080
#define NB     8
#define PH     28
#define PW     28
#define IMG    224
#define BM     128
#define BN     128
#define TPC    5
#define CHUNKS 47   // 47*5 = 235 tiles of 128 cols = 30080

using bf16x8_t = __attribute__((ext_vector_type(8))) __bf16;
using bf16x2_t = __attribute__((ext_vector_type(2))) __bf16;
using f32x4_t  = __attribute__((ext_vector_type(4))) float;
using f32x2_t  = __attribute__((ext_vector_type(2))) float;

// One wave per row: fp32 -> bf16 convert + row sum-of-squares.
// Pad rows (>= valid_rows): zeros in dst, +inf in sq (never wins the min).
__global__ __launch_bounds__(256) void prep_rows(const float* __restrict__ src,
                                                 __bf16* __restrict__ dst,
                                                 float* __restrict__ sq,
                                                 int valid_rows, int total_rows) {
    int wave = (blockIdx.x * blockDim.x + threadIdx.x) >> 6;
    int lane = threadIdx.x & 63;
    if (wave >= total_rows) return;
    float x = 0.f, y = 0.f;
    if (wave < valid_rows) {
        f32x2_t v = *(const f32x2_t*)(src + (size_t)wave * DIM + lane * 2);
        x = v.x; y = v.y;
    }
    float s = x * x + y * y;
    #pragma unroll
    for (int m = 1; m < 64; m <<= 1) s += __shfl_xor(s, m);
    bf16x2_t p; p.x = (__bf16)x; p.y = (__bf16)y;
    *(bf16x2_t*)(dst + (size_t)wave * DIM + lane * 2) = p;
    if (lane == 0) sq[wave] = (wave < valid_rows) ? s : INFINITY;
}

__global__ void init_nn(unsigned int* __restrict__ nn) {
    int i = blockIdx.x * 256 + threadIdx.x;
    if (i < N_FEAT) nn[i] = 0x7f800000u;  // +inf bits
}

// 4 waves/block; each wave owns 32 rows (2 m-frags of 16). A fragments live in
// registers for the whole block (K=128 total). Loop over TPC column tiles of
// 128 bank rows: stage 32KB into XOR-swizzled LDS, MFMA, fused (m2 - 2*dot)
// running min. Final: shuffle-min across lane&15, atomicMin on float bits.
__global__ __launch_bounds__(256) void dist_min_kernel(
        const __bf16* __restrict__ fbb, const __bf16* __restrict__ mbb,
        const float* __restrict__ f2, const float* __restrict__ m2,
        unsigned int* __restrict__ nn) {
    __shared__ __align__(16) unsigned char lds[BN * DIM * 2];  // 32KB
    const int tid   = threadIdx.x;
    const int lane  = tid & 63;
    const int w     = tid >> 6;
    const int row16 = lane & 15;
    const int kgrp  = lane >> 4;
    const int arow  = blockIdx.x * BM + w * 32;

    // A fragments: a[m][kk] = A[arow + m*16 + (lane&15)][kk*32 + kgrp*8 .. +7]
    bf16x8_t afrag[2][4];
    #pragma unroll
    for (int m = 0; m < 2; ++m)
        #pragma unroll
        for (int kk = 0; kk < 4; ++kk)
            afrag[m][kk] = *(const bf16x8_t*)(fbb + (size_t)(arow + m * 16 + row16) * DIM
                                              + kk * 32 + kgrp * 8);
    // f2 per accumulator element: row = arow + m*16 + kgrp*4 + j  (C/D layout)
    float f2v[2][4];
    #pragma unroll
    for (int m = 0; m < 2; ++m)
        #pragma unroll
        for (int j = 0; j < 4; ++j)
            f2v[m][j] = f2[arow + m * 16 + kgrp * 4 + j];

    float rmin[2][4];
    #pragma unroll
    for (int m = 0; m < 2; ++m)
        #pragma unroll
        for (int j = 0; j < 4; ++j) rmin[m][j] = INFINITY;

    for (int t = 0; t < TPC; ++t) {
        const int c0 = (blockIdx.y * TPC + t) * BN;
        __syncthreads();  // previous tile's reads done before overwrite
        const unsigned char* src = (const unsigned char*)(mbb + (size_t)c0 * DIM);
        // Stage 32KB: linear global (perfectly coalesced), swizzled LDS dest.
        #pragma unroll
        for (int i = 0; i < 8; ++i) {
            int linear = (i * 256 + tid) * 16;   // byte offset in tile
            int col = linear >> 8;               // bank-row within tile
            int kb  = linear & 255;
            int ldsoff = (col << 8) | (kb ^ ((col & 7) << 4));
            *(bf16x8_t*)(lds + ldsoff) = *(const bf16x8_t*)(src + linear);
        }
        __syncthreads();
        #pragma unroll
        for (int n = 0; n < 8; ++n) {
            const int col = n * 16 + row16;
            const float m2c = m2[c0 + col];
            bf16x8_t bfrag[4];
            #pragma unroll
            for (int kk = 0; kk < 4; ++kk) {
                int kb = kk * 64 + kgrp * 16;
                bfrag[kk] = *(const bf16x8_t*)(lds + ((col << 8) | (kb ^ ((col & 7) << 4))));
            }
            #pragma unroll
            for (int m = 0; m < 2; ++m) {
                f32x4_t acc = {0.f, 0.f, 0.f, 0.f};
                #pragma unroll
                for (int kk = 0; kk < 4; ++kk)
                    acc = __builtin_amdgcn_mfma_f32_16x16x32_bf16(afrag[m][kk], bfrag[kk],
                                                                  acc, 0, 0, 0);
                #pragma unroll
                for (int j = 0; j < 4; ++j)
                    rmin[m][j] = fminf(rmin[m][j], m2c - 2.0f * acc[j]);
            }
        }
    }
    #pragma unroll
    for (int m = 0; m < 2; ++m)
        #pragma unroll
        for (int j = 0; j < 4; ++j) {
            float v = rmin[m][j] + f2v[m][j];
            v = fminf(v, __shfl_xor(v, 1));
            v = fminf(v, __shfl_xor(v, 2));
            v = fminf(v, __shfl_xor(v, 4));
            v = fminf(v, __shfl_xor(v, 8));
            if (row16 == 0)
                atomicMin(nn + arow + m * 16 + kgrp * 4 + j, __float_as_uint(v));
        }
}

__global__ void image_max_kernel(const unsigned int* __restrict__ nn,
                                 float* __restrict__ out) {
    __shared__ float wmax[4];
    int b = blockIdx.x;
    int tid = threadIdx.x;
    float v = -INFINITY;
    for (int i = tid; i < PH * PW; i += 256)
        v = fmaxf(v, __uint_as_float(nn[b * PH * PW + i]));
    #pragma unroll
    for (int m = 1; m < 64; m <<= 1) v = fmaxf(v, __shfl_xor(v, m));
    if ((tid & 63) == 0) wmax[tid >> 6] = v;
    __syncthreads();
    if (tid == 0) out[b] = fmaxf(fmaxf(wmax[0], wmax[1]), fmaxf(wmax[2], wmax[3]));
}

// Half-pixel bilinear 28x28 -> 224x224 with edge clamp (== jax resize upsample).
__global__ void upsample_kernel(const unsigned int* __restrict__ nn,
                                float* __restrict__ up) {
    int idx = blockIdx.x * 256 + threadIdx.x;
    if (idx >= NB * IMG * IMG) return;
    int b = idx / (IMG * IMG);
    int rem = idx - b * (IMG * IMG);
    int y = rem / IMG;
    int x = rem - y * IMG;
    float sy = y * 0.125f - 0.4375f;
    float sx = x * 0.125f - 0.4375f;
    float fy = floorf(sy), fx = floorf(sx);
    float ty = sy - fy, tx = sx - fx;
    int y0 = (int)fy, x0 = (int)fx;
    int y1 = min(y0 + 1, PH - 1), x1 = min(x0 + 1, PW - 1);
    y0 = max(y0, 0); x0 = max(x0, 0);
    const unsigned int* p = nn + b * PH * PW;
    float v00 = __uint_as_float(p[y0 * PW + x0]);
    float v01 = __uint_as_float(p[y0 * PW + x1]);
    float v10 = __uint_as_float(p[y1 * PW + x0]);
    float v11 = __uint_as_float(p[y1 * PW + x1]);
    float v0 = v00 + tx * (v01 - v00);
    float v1 = v10 + tx * (v11 - v10);
    up[idx] = v0 + ty * (v1 - v0);
}

extern "C" void kernel_launch(void* const* d_in, const int* in_sizes, int n_in,
                              void* d_out, int out_size, void* d_ws, size_t ws_size,
                              hipStream_t stream) {
    const float* feat = (const float*)d_in[0];   // [6272,128] f32
    const float* bank = (const float*)d_in[1];   // [30000,128] f32
    char* ws = (char*)d_ws;
    // workspace layout (256B-aligned offsets), total ~9.48 MB
    __bf16*       mbb = (__bf16*)(ws + 0);           // 30080*128*2 = 7,700,480
    __bf16*       fbb = (__bf16*)(ws + 7700480);     // 6272*128*2  = 1,605,632
    float*        m2  = (float*)(ws + 9306112);      // 30080*4     =   120,320
    float*        f2  = (float*)(ws + 9426432);      // 6272*4      =    25,088
    unsigned int* nn  = (unsigned int*)(ws + 9451520); // 6272*4    =    25,088
    float* out_scores = (float*)d_out;               // [8]
    float* out_up     = out_scores + NB;             // [8,224,224]

    hipLaunchKernelGGL(prep_rows, dim3(M_PAD / 4), dim3(256), 0, stream,
                       bank, mbb, m2, M_BANK, M_PAD);
    hipLaunchKernelGGL(prep_rows, dim3(N_FEAT / 4), dim3(256), 0, stream,
                       feat, fbb, f2, N_FEAT, N_FEAT);
    hipLaunchKernelGGL(init_nn, dim3((N_FEAT + 255) / 256), dim3(256), 0, stream, nn);
    hipLaunchKernelGGL(dist_min_kernel, dim3(N_FEAT / BM, CHUNKS), dim3(256), 0, stream,
                       fbb, mbb, f2, m2, nn);
    hipLaunchKernelGGL(image_max_kernel, dim3(NB), dim3(256), 0, stream, nn, out_scores);
    hipLaunchKernelGGL(upsample_kernel, dim3((NB * IMG * IMG + 255) / 256), dim3(256), 0,
                       stream, nn, out_up);
}